// Round 6
// baseline (320.542 us; speedup 1.0000x reference)
//
#include <hip/hip_runtime.h>
#include <hip/hip_bf16.h>

// RNN: B=1024, T=512, E=64, H=128, OUT=2, VOCAB=4411
// R6 (from R5's 204us @ 959cyc/step; model says ~470 is reachable):
//  1. h stored in EXACT B-fragment order: off(b,k) = (k>>5)*512
//     + (((k>>3)&3)*16+b)*8 + (k&7) ushorts. Wave reads bfrag[kt] at
//     rbuf + kt*512 + L*8 -> lane-sequential 16B/lane, zero bank conflicts
//     by construction (R5's stride-136 cost 97 cyc/step: 3.19M conflicts).
//     Writes: 2 words/lane @ 4-word stride = minimum bank cycles.
//  2. Token pipeline 1 stage deeper: tok[t+3] -> register each step, so the
//     pe gather for t+2 issues with ZERO lgkm dependency.
//  3. Explicit 2x unroll (ht0->ht1, ht1->ht0): no register rotation movs.
//  4. __float22bfloat162_rn packed convert (2 instr/jt vs 6 scalar).
//  5. pe_kernel PV=8 (552 blocks) for occupancy.
// Barrier stays lgkm-only (R5's key win): pe gathers never drained.
// MFMA 16x16x32_bf16 (m89/m91): A[m][k]: m=L&15,k=(L>>4)*8+s; B[k][n]:
// n=L&15,k=(L>>4)*8+s; D[m][n]: n=L&15,m=(L>>4)*4+reg.

constexpr int Bc    = 1024;
constexpr int Tc    = 512;
constexpr int Ec    = 64;
constexpr int Hc    = 128;
constexpr int OUTc  = 2;
constexpr int VOCAB = 4411;

typedef short  short8  __attribute__((ext_vector_type(8)));
typedef float  floatx4 __attribute__((ext_vector_type(4)));

__device__ __forceinline__ unsigned short f2bf(float x) {
    union { __hip_bfloat16 h; unsigned short u; } v;
    v.h = __float2bfloat16(x);
    return v.u;
}
__device__ __forceinline__ float bf2f(unsigned short u) {
    union { float f; unsigned int u; } c;
    c.u = ((unsigned int)u) << 16;
    return c.f;
}
__device__ __forceinline__ unsigned int pack2bf(float lo, float hi) {
    union { __hip_bfloat162 h; unsigned int u; } c;
    c.h = __float22bfloat162_rn(float2{lo, hi});   // lo -> low 16 bits
    return c.u;
}
// tanh(z) = 1 - 2*rcp(exp2(k*z)+1); division-free, exact at saturation.
__device__ __forceinline__ float fast_tanh(float z) {
    const float e = __builtin_amdgcn_exp2f(2.8853900817779268f * z);
    return 1.0f - 2.0f * __builtin_amdgcn_rcpf(e + 1.0f);
}

// Workgroup barrier draining ONLY lgkmcnt (LDS); global loads stay in flight.
#define LGKM_BARRIER() asm volatile("s_waitcnt lgkmcnt(0)\n\ts_barrier" ::: "memory")

// ---------------- Kernel 1: pe[v][j] = emb[v].W_ih[j] + b_ih[j] + b_hh[j] ----
constexpr int PV = 8;
__global__ __launch_bounds__(Hc) void pe_kernel(
    const float* __restrict__ emb, const float* __restrict__ W_ih,
    const float* __restrict__ b_ih, const float* __restrict__ b_hh,
    float* __restrict__ pe)
{
    const int j  = threadIdx.x;
    const int v0 = blockIdx.x * PV;

    __shared__ float es[PV * Ec];   // 2 KB
    for (int i = j; i < PV * Ec / 4; i += Hc) {
        const int flat = i * 4, vv = flat >> 6;
        if (v0 + vv < VOCAB)
            *(float4*)&es[flat] = *(const float4*)(emb + (long)(v0 + vv) * Ec + (flat & 63));
    }

    float4 wr[Ec / 4];
#pragma unroll
    for (int e = 0; e < Ec / 4; ++e)
        wr[e] = *(const float4*)(W_ih + j * Ec + e * 4);
    const float bias = b_ih[j] + b_hh[j];

    __syncthreads();

    for (int vv = 0; vv < PV; ++vv) {
        if (v0 + vv >= VOCAB) break;
        const float* er = &es[vv * Ec];
        float a0 = bias, a1 = 0.f, a2 = 0.f, a3 = 0.f;
#pragma unroll
        for (int e = 0; e < Ec / 4; ++e) {
            const float4 E = *(const float4*)(er + 4 * e);  // LDS broadcast
            a0 = fmaf(E.x, wr[e].x, a0);
            a1 = fmaf(E.y, wr[e].y, a1);
            a2 = fmaf(E.z, wr[e].z, a2);
            a3 = fmaf(E.w, wr[e].w, a3);
        }
        pe[(long)(v0 + vv) * Hc + j] = (a0 + a1) + (a2 + a3);
    }
}

// ---------------- Kernel 2: MFMA recurrence ----------------
constexpr int HT_BUF     = 2048;  // ushorts per h buffer (4 frag-tiles x 512)
constexpr int TOK_STRIDE = 513;   // ints per b-row (pad: banks (b+t)&31, no conflict)

__global__ __attribute__((amdgpu_flat_work_group_size(256, 256)))
void rnn_mfma(
    const int*   __restrict__ inputs,  // [B, T]
    const float* __restrict__ pe,      // [VOCAB, H]
    const float* __restrict__ W_hh,    // [H, H]
    const float* __restrict__ W_lin,   // [OUT, H]
    const float* __restrict__ b_lin,   // [OUT]
    float* __restrict__ out)           // [B, OUT]
{
    const int tid = threadIdx.x;
    const int w   = tid >> 6;      // wave 0..3 -> j in [32w, 32w+32)
    const int L   = tid & 63;
    const int q   = L >> 4;        // 0..3
    const int b   = L & 15;        // batch sub-row / MFMA col
    const int blk = blockIdx.x;
    const int jb  = w * 32;

    __shared__ __align__(16) unsigned short HT[2 * HT_BUF];
    __shared__ int toks[16 * TOK_STRIDE];

    // Stage 16 token rows (32 KB) into LDS, coalesced.
    {
        const int base = blk * 16 * Tc;
        for (int i = tid; i < 16 * Tc / 4; i += 256) {
            const int4 v4 = *(const int4*)(inputs + base + i * 4);
            const int bb = (i * 4) >> 9, t0 = (i * 4) & 511;
            int* dst = &toks[bb * TOK_STRIDE + t0];
            dst[0] = v4.x; dst[1] = v4.y; dst[2] = v4.z; dst[3] = v4.w;
        }
    }
    // Zero h buffer 0 (h_0 = 0).
    {
        unsigned int* z = (unsigned int*)HT;
        for (int i = tid; i < HT_BUF / 2; i += 256) z[i] = 0u;
    }

    // Static A fragments: W_hh rows [jb, jb+32) as bf16 (2x4 frags, 32 VGPR).
    short8 wfrag[2][4];
#pragma unroll
    for (int jt = 0; jt < 2; ++jt) {
        const float* wr = W_hh + (jb + jt * 16 + b) * Hc;   // A row m = L&15
#pragma unroll
        for (int kt = 0; kt < 4; ++kt) {
            const float4 w0 = *(const float4*)(wr + kt * 32 + q * 8);
            const float4 w1 = *(const float4*)(wr + kt * 32 + q * 8 + 4);
            union { short8 s; unsigned short u[8]; } uf;
            uf.u[0] = f2bf(w0.x); uf.u[1] = f2bf(w0.y);
            uf.u[2] = f2bf(w0.z); uf.u[3] = f2bf(w0.w);
            uf.u[4] = f2bf(w1.x); uf.u[5] = f2bf(w1.y);
            uf.u[6] = f2bf(w1.z); uf.u[7] = f2bf(w1.w);
            wfrag[jt][kt] = uf.s;
        }
    }
#pragma unroll
    for (int jt = 0; jt < 2; ++jt)
        asm volatile("" : "+v"(wfrag[jt][0]), "+v"(wfrag[jt][1]),
                          "+v"(wfrag[jt][2]), "+v"(wfrag[jt][3]));

    unsigned short* const ht0 = HT;
    unsigned short* const ht1 = HT + HT_BUF;
    const int rd_base = L * 8;           // + kt*512: lane-sequential, 0 conflicts
    int wr_off[2];
#pragma unroll
    for (int jt = 0; jt < 2; ++jt) {     // j0 = jb+jt*16+q*4 -> B-frag-order addr
        const int j0 = jb + jt * 16 + q * 4;
        wr_off[jt] = ((j0 >> 5) << 9) + (((j0 >> 3) & 3) * 16 + b) * 8 + (j0 & 7);
    }

    const int* tr = &toks[b * TOK_STRIDE];

    __syncthreads();   // tokens + zeroed h0 visible (one-time full drain)

    // Prologue: xp for t=0,1 in flight; token for t=2 in a register.
    float4 xpA[2], xpB[2];
    int tk;
    {
        const int t0 = tr[0], t1 = tr[1];
        tk = tr[2];
#pragma unroll
        for (int jt = 0; jt < 2; ++jt) {
            xpA[jt] = *(const float4*)(pe + (long)t0 * Hc + jb + jt * 16 + q * 4);
            xpB[jt] = *(const float4*)(pe + (long)t1 * Hc + jb + jt * 16 + q * 4);
        }
    }

#define RNN_STEP(T, RB, WB, XC)                                                  \
    {                                                                            \
        short8 bfrag[4];                                                         \
        _Pragma("unroll")                                                        \
        for (int kt = 0; kt < 4; ++kt)                                           \
            bfrag[kt] = *(const short8*)((RB) + kt * 512 + rd_base);             \
        const int tknew = tr[((T) + 3 < Tc) ? ((T) + 3) : (Tc - 1)];             \
        floatx4 acc[2];                                                          \
        _Pragma("unroll")                                                        \
        for (int jt = 0; jt < 2; ++jt)                                           \
            acc[jt] = (floatx4){XC[jt].x, XC[jt].y, XC[jt].z, XC[jt].w};         \
        _Pragma("unroll")                                                        \
        for (int jt = 0; jt < 2; ++jt)                                           \
            XC[jt] = *(const float4*)(pe + (long)tk * Hc + jb + jt * 16 + q * 4);\
        tk = tknew;                                                              \
        _Pragma("unroll")                                                        \
        for (int kt = 0; kt < 4; ++kt) {                                         \
            acc[0] = __builtin_amdgcn_mfma_f32_16x16x32_bf16(                    \
                wfrag[0][kt], bfrag[kt], acc[0], 0, 0, 0);                       \
            acc[1] = __builtin_amdgcn_mfma_f32_16x16x32_bf16(                    \
                wfrag[1][kt], bfrag[kt], acc[1], 0, 0, 0);                       \
        }                                                                        \
        _Pragma("unroll")                                                        \
        for (int jt = 0; jt < 2; ++jt) {                                         \
            const float h0 = fast_tanh(acc[jt][0]);                              \
            const float h1 = fast_tanh(acc[jt][1]);                              \
            const float h2 = fast_tanh(acc[jt][2]);                              \
            const float h3 = fast_tanh(acc[jt][3]);                              \
            uint2 pk;                                                            \
            pk.x = pack2bf(h0, h1);                                              \
            pk.y = pack2bf(h2, h3);                                              \
            *(uint2*)((WB) + wr_off[jt]) = pk;                                   \
        }                                                                        \
        LGKM_BARRIER();                                                          \
    }

    for (int t = 0; t < Tc; t += 2) {
        RNN_STEP(t,     ht0, ht1, xpA);   // consumes xp[t],   refills for t+2
        RNN_STEP(t + 1, ht1, ht0, xpB);   // consumes xp[t+1], refills for t+3
    }
#undef RNN_STEP

    // Final h is in ht0 (t=511 wrote ht0), B-fragment order. Linear head.
    if (tid < 16 * OUTc) {
        const int bb = tid >> 1, o = tid & 1;
        float s = b_lin[o];
        const float* wl = W_lin + o * Hc;
#pragma unroll 8
        for (int k = 0; k < Hc; ++k) {
            const int off = ((k >> 5) << 9) + (((k >> 3) & 3) * 16 + bb) * 8 + (k & 7);
            s = fmaf(bf2f(ht0[off]), wl[k], s);
        }
        out[(blk * 16 + bb) * OUTc + o] = s;
    }
}

extern "C" void kernel_launch(void* const* d_in, const int* in_sizes, int n_in,
                              void* d_out, int out_size, void* d_ws, size_t ws_size,
                              hipStream_t stream) {
    const int*   inputs    = (const int*)d_in[0];
    const float* emb_table = (const float*)d_in[1];
    const float* W_ih      = (const float*)d_in[2];
    const float* W_hh      = (const float*)d_in[3];
    const float* b_ih      = (const float*)d_in[4];
    const float* b_hh      = (const float*)d_in[5];
    const float* W_lin     = (const float*)d_in[6];
    const float* b_lin     = (const float*)d_in[7];
    float* out = (float*)d_out;

    float* pe = (float*)d_ws;  // VOCAB*H*4 = 2.26 MB
    pe_kernel<<<(VOCAB + PV - 1) / PV, Hc, 0, stream>>>(emb_table, W_ih, b_ih, b_hh, pe);
    rnn_mfma<<<Bc / 16, 256, 0, stream>>>(inputs, pe, W_hh, W_lin, b_lin, out);
}

// Round 7
// 281.538 us; speedup vs baseline: 1.1385x; 1.1385x over previous
//
#include <hip/hip_runtime.h>
#include <hip/hip_bf16.h>

// RNN: B=1024, T=512, E=64, H=128, OUT=2, VOCAB=4411
// R7 = R5 skeleton VERBATIM (204.7us, compiler schedules it well) with only
// address/order-level deltas (R6's loop restructuring regressed to 250us by
// perturbing waitcnt placement -> exposed ~200cyc L2 latency per step):
//  1. h stored in EXACT B-fragment order: addr(k,n) = (k>>5)*512
//     + (((k>>3)&3)*16+n)*8 + (k&7) ushorts. Wave reads bfrag[kt] at
//     kt*512 + L*8 -> lane-sequential 16B/lane, zero bank conflicts by
//     construction; writes = contiguous non-overlapping dword pairs.
//  2. kt-outer MFMA order: acc[0]/acc[1] alternate -> 2 independent 4-deep
//     dependency chains instead of 2 sequential ones.
//  3. pe_kernel back to simple R3 form (lowest observed overhead).
// Barrier stays lgkm-only (R5's key win): pe gathers never drained.
// MFMA 16x16x32_bf16 (m89/m91): A[m][k]: m=L&15,k=(L>>4)*8+s; B[k][n]:
// n=L&15,k=(L>>4)*8+s; D[m][n]: n=L&15,m=(L>>4)*4+reg.

constexpr int Bc    = 1024;
constexpr int Tc    = 512;
constexpr int Ec    = 64;
constexpr int Hc    = 128;
constexpr int OUTc  = 2;
constexpr int VOCAB = 4411;

typedef short  short8  __attribute__((ext_vector_type(8)));
typedef float  floatx4 __attribute__((ext_vector_type(4)));

__device__ __forceinline__ unsigned short f2bf(float x) {
    union { __hip_bfloat16 h; unsigned short u; } v;
    v.h = __float2bfloat16(x);
    return v.u;
}
__device__ __forceinline__ float bf2f(unsigned short u) {
    union { float f; unsigned int u; } c;
    c.u = ((unsigned int)u) << 16;
    return c.f;
}
__device__ __forceinline__ unsigned int pack2bf(float lo, float hi) {
    union { __hip_bfloat162 h; unsigned int u; } c;
    c.h = __float22bfloat162_rn(float2{lo, hi});   // lo -> low 16 bits
    return c.u;
}
// tanh(z) = 1 - 2*rcp(exp2(k*z)+1); division-free, exact at saturation.
__device__ __forceinline__ float fast_tanh(float z) {
    const float e = __builtin_amdgcn_exp2f(2.8853900817779268f * z);
    return 1.0f - 2.0f * __builtin_amdgcn_rcpf(e + 1.0f);
}

// Workgroup barrier draining ONLY lgkmcnt (LDS); global loads stay in flight.
#define LGKM_BARRIER() asm volatile("s_waitcnt lgkmcnt(0)\n\ts_barrier" ::: "memory")

// ---------------- Kernel 1: pe[v][j] = emb[v].W_ih[j] + b_ih[j] + b_hh[j] ----
// Simple R3 form: one vocab row per block, broadcast emb reads (L1/L2-hot).
__global__ __launch_bounds__(Hc) void pe_kernel(
    const float* __restrict__ emb, const float* __restrict__ W_ih,
    const float* __restrict__ b_ih, const float* __restrict__ b_hh,
    float* __restrict__ pe)
{
    const int v = blockIdx.x;
    const int j = threadIdx.x;
    const float* er = emb + (long)v * Ec;
    const float* wr = W_ih + j * Ec;
    float a0 = b_ih[j] + b_hh[j], a1 = 0.f, a2 = 0.f, a3 = 0.f;
#pragma unroll
    for (int e = 0; e < Ec; e += 4) {
        const float4 E = *(const float4*)(er + e);
        const float4 W = *(const float4*)(wr + e);
        a0 = fmaf(E.x, W.x, a0);
        a1 = fmaf(E.y, W.y, a1);
        a2 = fmaf(E.z, W.z, a2);
        a3 = fmaf(E.w, W.w, a3);
    }
    pe[(long)v * Hc + j] = (a0 + a1) + (a2 + a3);
}

// ---------------- Kernel 2: MFMA recurrence ----------------
constexpr int HT_BUF     = 2048;  // ushorts per h buffer (4 k-tiles x 512)
constexpr int TOK_STRIDE = 513;   // ints per b-row

__global__ __attribute__((amdgpu_flat_work_group_size(256, 256)))
void rnn_mfma(
    const int*   __restrict__ inputs,  // [B, T]
    const float* __restrict__ pe,      // [VOCAB, H]
    const float* __restrict__ W_hh,    // [H, H]
    const float* __restrict__ W_lin,   // [OUT, H]
    const float* __restrict__ b_lin,   // [OUT]
    float* __restrict__ out)           // [B, OUT]
{
    const int tid = threadIdx.x;
    const int w   = tid >> 6;      // wave 0..3 -> j in [32w, 32w+32)
    const int L   = tid & 63;
    const int q   = L >> 4;        // 0..3
    const int b   = L & 15;        // batch sub-row / MFMA col
    const int blk = blockIdx.x;
    const int jb  = w * 32;

    __shared__ __align__(16) unsigned short HT[2 * HT_BUF];
    __shared__ int toks[16 * TOK_STRIDE];

    // Stage 16 token rows (32 KB) into LDS, coalesced.
    {
        const int base = blk * 16 * Tc;
        for (int i = tid; i < 16 * Tc / 4; i += 256) {
            const int4 v4 = *(const int4*)(inputs + base + i * 4);
            const int bb = (i * 4) >> 9, t0 = (i * 4) & 511;
            int* dst = &toks[bb * TOK_STRIDE + t0];
            dst[0] = v4.x; dst[1] = v4.y; dst[2] = v4.z; dst[3] = v4.w;
        }
    }
    // Zero h buffer 0 (h_0 = 0): 1024 dwords = all of ht0.
    {
        unsigned int* z = (unsigned int*)HT;
        for (int i = tid; i < HT_BUF / 2; i += 256) z[i] = 0u;
    }

    // Static A fragments: W_hh rows [jb, jb+32) as bf16 (2x4 frags, 32 VGPR).
    short8 wfrag[2][4];
#pragma unroll
    for (int jt = 0; jt < 2; ++jt) {
        const float* wr = W_hh + (jb + jt * 16 + b) * Hc;   // A row m = L&15
#pragma unroll
        for (int kt = 0; kt < 4; ++kt) {
            const float4 w0 = *(const float4*)(wr + kt * 32 + q * 8);
            const float4 w1 = *(const float4*)(wr + kt * 32 + q * 8 + 4);
            union { short8 s; unsigned short u[8]; } uf;
            uf.u[0] = f2bf(w0.x); uf.u[1] = f2bf(w0.y);
            uf.u[2] = f2bf(w0.z); uf.u[3] = f2bf(w0.w);
            uf.u[4] = f2bf(w1.x); uf.u[5] = f2bf(w1.y);
            uf.u[6] = f2bf(w1.z); uf.u[7] = f2bf(w1.w);
            wfrag[jt][kt] = uf.s;
        }
    }
#pragma unroll
    for (int jt = 0; jt < 2; ++jt)
        asm volatile("" : "+v"(wfrag[jt][0]), "+v"(wfrag[jt][1]),
                          "+v"(wfrag[jt][2]), "+v"(wfrag[jt][3]));

    unsigned short* const ht0 = HT;
    unsigned short* const ht1 = HT + HT_BUF;
    const int rd_base = L * 8;          // + kt*512: lane-sequential, 0 conflicts
    int wr_off[2];
#pragma unroll
    for (int jt = 0; jt < 2; ++jt) {    // j0 = jb+jt*16+q*4 in B-frag order
        const int j0 = jb + jt * 16 + q * 4;
        wr_off[jt] = ((j0 >> 5) << 9) + (((j0 >> 3) & 3) * 16 + b) * 8 + (j0 & 7);
    }

    const int* tr = &toks[b * TOK_STRIDE];

    __syncthreads();   // tokens + zeroed h0 visible (one-time full drain)

    // Prologue: xp for t=0 and t=1.
    float4 xpc[2], xpn[2];
    {
        const int t0 = tr[0], t1 = tr[1];
#pragma unroll
        for (int jt = 0; jt < 2; ++jt) {
            xpc[jt] = *(const float4*)(pe + (long)t0 * Hc + jb + jt * 16 + q * 4);
            xpn[jt] = *(const float4*)(pe + (long)t1 * Hc + jb + jt * 16 + q * 4);
        }
    }

    for (int t = 0; t < Tc; ++t) {
        unsigned short* const rbuf = (t & 1) ? ht1 : ht0;
        unsigned short* const wbuf = (t & 1) ? ht0 : ht1;

        // B fragments: h bf16, lane-sequential (conflict-free by construction).
        short8 bfrag[4];
#pragma unroll
        for (int kt = 0; kt < 4; ++kt)
            bfrag[kt] = *(const short8*)(rbuf + kt * 512 + rd_base);

        // Prefetch pe row for t+2 (stays in flight across the lgkm barrier).
        float4 xp2[2];
        {
            const int tk = tr[(t + 2 < Tc) ? (t + 2) : (Tc - 1)];
#pragma unroll
            for (int jt = 0; jt < 2; ++jt)
                xp2[jt] = *(const float4*)(pe + (long)tk * Hc + jb + jt * 16 + q * 4);
        }

        // 8 MFMAs, kt-outer: acc[0]/acc[1] alternate -> 2 independent chains.
        floatx4 acc[2];
        acc[0] = (floatx4){xpc[0].x, xpc[0].y, xpc[0].z, xpc[0].w};
        acc[1] = (floatx4){xpc[1].x, xpc[1].y, xpc[1].z, xpc[1].w};
#pragma unroll
        for (int kt = 0; kt < 4; ++kt) {
            acc[0] = __builtin_amdgcn_mfma_f32_16x16x32_bf16(
                wfrag[0][kt], bfrag[kt], acc[0], 0, 0, 0);
            acc[1] = __builtin_amdgcn_mfma_f32_16x16x32_bf16(
                wfrag[1][kt], bfrag[kt], acc[1], 0, 0, 0);
        }

        // tanh -> bf16 -> one b64 LDS write per jt (B-fragment order).
#pragma unroll
        for (int jt = 0; jt < 2; ++jt) {
            const float h0 = fast_tanh(acc[jt][0]);
            const float h1 = fast_tanh(acc[jt][1]);
            const float h2 = fast_tanh(acc[jt][2]);
            const float h3 = fast_tanh(acc[jt][3]);
            uint2 pk;
            pk.x = pack2bf(h0, h1);
            pk.y = pack2bf(h2, h3);
            *(uint2*)(wbuf + wr_off[jt]) = pk;
        }

        LGKM_BARRIER();   // drains LDS only; pe prefetch stays outstanding

        xpc[0] = xpn[0]; xpc[1] = xpn[1];
        xpn[0] = xp2[0]; xpn[1] = xp2[1];
    }

    // Final h is in ht0 (t=511 wrote ht0), B-fragment order. Linear head.
    if (tid < 16 * OUTc) {
        const int bb = tid >> 1, o = tid & 1;
        float s = b_lin[o];
        const float* wl = W_lin + o * Hc;
#pragma unroll 8
        for (int k = 0; k < Hc; ++k) {
            const int off = ((k >> 5) << 9) + (((k >> 3) & 3) * 16 + bb) * 8 + (k & 7);
            s = fmaf(bf2f(ht0[off]), wl[k], s);
        }
        out[(blk * 16 + bb) * OUTc + o] = s;
    }
}

extern "C" void kernel_launch(void* const* d_in, const int* in_sizes, int n_in,
                              void* d_out, int out_size, void* d_ws, size_t ws_size,
                              hipStream_t stream) {
    const int*   inputs    = (const int*)d_in[0];
    const float* emb_table = (const float*)d_in[1];
    const float* W_ih      = (const float*)d_in[2];
    const float* W_hh      = (const float*)d_in[3];
    const float* b_ih      = (const float*)d_in[4];
    const float* b_hh      = (const float*)d_in[5];
    const float* W_lin     = (const float*)d_in[6];
    const float* b_lin     = (const float*)d_in[7];
    float* out = (float*)d_out;

    float* pe = (float*)d_ws;  // VOCAB*H*4 = 2.26 MB
    pe_kernel<<<VOCAB, Hc, 0, stream>>>(emb_table, W_ih, b_ih, b_hh, pe);
    rnn_mfma<<<Bc / 16, 256, 0, stream>>>(inputs, pe, W_hh, W_lin, b_lin, out);
}

// Round 8
// 245.512 us; speedup vs baseline: 1.3056x; 1.1467x over previous
//
#include <hip/hip_runtime.h>
#include <hip/hip_bf16.h>

// RNN: B=1024, T=512, E=64, H=128, OUT=2, VOCAB=4411
// R8 = R7 skeleton with the wave->work mapping re-cut (R7 post-mortem:
// ~945cyc/step = ~40% VALU issue [tanh transcendentals dominate] + ~13% MFMA
// + ~50% exposed latency with only 1 wave/SIMD):
//  1. 512 threads = 8 waves; wave w owns j in [16w, 16w+16). Per-lane tanh
//     drops 8 -> 4 values (halves the biggest issue term); 2 waves/SIMD
//     co-schedule (m114) to fill the read/MFMA/barrier stalls.
//  2. Split-K accumulators: acc0 = mfma(kt1, mfma(kt0, C=xp)), acc1 =
//     mfma(kt3, mfma(kt2, C=0)). Dep chain 4->2 MFMAs; C-operand seeding
//     removes the per-step acc-init movs. z = acc0+acc1.
//  3. One float4 xp load/lane/step (was 2).
// Everything else identical: lgkm-only barrier (pe loads never drained),
// B-fragment-order h in LDS (conflict-free reads), token LDS staging,
// depth-2 xp pipeline + register token.
// MFMA 16x16x32_bf16 (m89/m91): A[m][k]: m=L&15,k=(L>>4)*8+s; B[k][n]:
// n=L&15,k=(L>>4)*8+s; D[m][n]: n=L&15,m=(L>>4)*4+reg.

constexpr int Bc    = 1024;
constexpr int Tc    = 512;
constexpr int Ec    = 64;
constexpr int Hc    = 128;
constexpr int OUTc  = 2;
constexpr int VOCAB = 4411;

typedef short  short8  __attribute__((ext_vector_type(8)));
typedef float  floatx4 __attribute__((ext_vector_type(4)));

__device__ __forceinline__ unsigned short f2bf(float x) {
    union { __hip_bfloat16 h; unsigned short u; } v;
    v.h = __float2bfloat16(x);
    return v.u;
}
__device__ __forceinline__ float bf2f(unsigned short u) {
    union { float f; unsigned int u; } c;
    c.u = ((unsigned int)u) << 16;
    return c.f;
}
__device__ __forceinline__ unsigned int pack2bf(float lo, float hi) {
    union { __hip_bfloat162 h; unsigned int u; } c;
    c.h = __float22bfloat162_rn(float2{lo, hi});   // lo -> low 16 bits
    return c.u;
}
// tanh(z) = 1 - 2*rcp(exp2(k*z)+1); division-free, exact at saturation.
__device__ __forceinline__ float fast_tanh(float z) {
    const float e = __builtin_amdgcn_exp2f(2.8853900817779268f * z);
    return 1.0f - 2.0f * __builtin_amdgcn_rcpf(e + 1.0f);
}

// Workgroup barrier draining ONLY lgkmcnt (LDS); global loads stay in flight.
#define LGKM_BARRIER() asm volatile("s_waitcnt lgkmcnt(0)\n\ts_barrier" ::: "memory")

// ---------------- Kernel 1: pe[v][j] = emb[v].W_ih[j] + b_ih[j] + b_hh[j] ----
__global__ __launch_bounds__(Hc) void pe_kernel(
    const float* __restrict__ emb, const float* __restrict__ W_ih,
    const float* __restrict__ b_ih, const float* __restrict__ b_hh,
    float* __restrict__ pe)
{
    const int v = blockIdx.x;
    const int j = threadIdx.x;
    const float* er = emb + (long)v * Ec;
    const float* wr = W_ih + j * Ec;
    float a0 = b_ih[j] + b_hh[j], a1 = 0.f, a2 = 0.f, a3 = 0.f;
#pragma unroll
    for (int e = 0; e < Ec; e += 4) {
        const float4 E = *(const float4*)(er + e);
        const float4 W = *(const float4*)(wr + e);
        a0 = fmaf(E.x, W.x, a0);
        a1 = fmaf(E.y, W.y, a1);
        a2 = fmaf(E.z, W.z, a2);
        a3 = fmaf(E.w, W.w, a3);
    }
    pe[(long)v * Hc + j] = (a0 + a1) + (a2 + a3);
}

// ---------------- Kernel 2: MFMA recurrence ----------------
constexpr int HT_BUF     = 2048;  // ushorts per h buffer (4 k-tiles x 512)
constexpr int TOK_STRIDE = 513;   // ints per b-row

__global__ __attribute__((amdgpu_flat_work_group_size(512, 512)))
void rnn_mfma(
    const int*   __restrict__ inputs,  // [B, T]
    const float* __restrict__ pe,      // [VOCAB, H]
    const float* __restrict__ W_hh,    // [H, H]
    const float* __restrict__ W_lin,   // [OUT, H]
    const float* __restrict__ b_lin,   // [OUT]
    float* __restrict__ out)           // [B, OUT]
{
    const int tid = threadIdx.x;
    const int w   = tid >> 6;      // wave 0..7 -> j in [16w, 16w+16)
    const int L   = tid & 63;
    const int q   = L >> 4;        // 0..3
    const int b   = L & 15;        // batch sub-row / MFMA col
    const int blk = blockIdx.x;
    const int jb  = w * 16;

    __shared__ __align__(16) unsigned short HT[2 * HT_BUF];
    __shared__ int toks[16 * TOK_STRIDE];

    // Stage 16 token rows (32 KB) into LDS, coalesced.
    {
        const int base = blk * 16 * Tc;
        for (int i = tid; i < 16 * Tc / 4; i += 512) {
            const int4 v4 = *(const int4*)(inputs + base + i * 4);
            const int bb = (i * 4) >> 9, t0 = (i * 4) & 511;
            int* dst = &toks[bb * TOK_STRIDE + t0];
            dst[0] = v4.x; dst[1] = v4.y; dst[2] = v4.z; dst[3] = v4.w;
        }
    }
    // Zero h buffer 0 (h_0 = 0): 1024 dwords = all of ht0.
    {
        unsigned int* z = (unsigned int*)HT;
        for (int i = tid; i < HT_BUF / 2; i += 512) z[i] = 0u;
    }

    // Static A fragments: W_hh rows [jb, jb+16) as bf16 (4 frags, 16 VGPR).
    short8 wfrag[4];
    {
        const float* wr = W_hh + (jb + b) * Hc;             // A row m = L&15
#pragma unroll
        for (int kt = 0; kt < 4; ++kt) {
            const float4 w0 = *(const float4*)(wr + kt * 32 + q * 8);
            const float4 w1 = *(const float4*)(wr + kt * 32 + q * 8 + 4);
            union { short8 s; unsigned short u[8]; } uf;
            uf.u[0] = f2bf(w0.x); uf.u[1] = f2bf(w0.y);
            uf.u[2] = f2bf(w0.z); uf.u[3] = f2bf(w0.w);
            uf.u[4] = f2bf(w1.x); uf.u[5] = f2bf(w1.y);
            uf.u[6] = f2bf(w1.z); uf.u[7] = f2bf(w1.w);
            wfrag[kt] = uf.s;
        }
    }
    asm volatile("" : "+v"(wfrag[0]), "+v"(wfrag[1]),
                      "+v"(wfrag[2]), "+v"(wfrag[3]));

    unsigned short* const ht0 = HT;
    unsigned short* const ht1 = HT + HT_BUF;
    const int rd_base = L * 8;          // + kt*512: lane-sequential, 0 conflicts
    // Write offset: lane owns z[j0..j0+3][b], j0 = jb + q*4, B-frag order.
    const int j0     = jb + q * 4;
    const int wr_off = ((j0 >> 5) << 9) + (((j0 >> 3) & 3) * 16 + b) * 8 + (j0 & 7);
    const int xp_off = jb + q * 4;      // pe column base for this lane

    const int* tr = &toks[b * TOK_STRIDE];
    const floatx4 zac = (floatx4){0.f, 0.f, 0.f, 0.f};

    __syncthreads();   // tokens + zeroed h0 visible (one-time full drain)

    // Prologue: xp for t=0 and t=1.
    float4 xpc, xpn;
    {
        const int t0 = tr[0], t1 = tr[1];
        xpc = *(const float4*)(pe + (long)t0 * Hc + xp_off);
        xpn = *(const float4*)(pe + (long)t1 * Hc + xp_off);
    }

    for (int t = 0; t < Tc; ++t) {
        unsigned short* const rbuf = (t & 1) ? ht1 : ht0;
        unsigned short* const wbuf = (t & 1) ? ht0 : ht1;

        // B fragments: h bf16, lane-sequential (conflict-free by construction).
        short8 bfrag[4];
#pragma unroll
        for (int kt = 0; kt < 4; ++kt)
            bfrag[kt] = *(const short8*)(rbuf + kt * 512 + rd_base);

        // Prefetch pe row for t+2 (stays in flight across the lgkm barrier).
        float4 xp2;
        {
            const int tk = tr[(t + 2 < Tc) ? (t + 2) : (Tc - 1)];
            xp2 = *(const float4*)(pe + (long)tk * Hc + xp_off);
        }

        // Split-K: two independent 2-deep MFMA chains, C-operand seeded.
        floatx4 acc0 = (floatx4){xpc.x, xpc.y, xpc.z, xpc.w};
        acc0 = __builtin_amdgcn_mfma_f32_16x16x32_bf16(wfrag[0], bfrag[0], acc0, 0, 0, 0);
        floatx4 acc1 = __builtin_amdgcn_mfma_f32_16x16x32_bf16(wfrag[2], bfrag[2], zac, 0, 0, 0);
        acc0 = __builtin_amdgcn_mfma_f32_16x16x32_bf16(wfrag[1], bfrag[1], acc0, 0, 0, 0);
        acc1 = __builtin_amdgcn_mfma_f32_16x16x32_bf16(wfrag[3], bfrag[3], acc1, 0, 0, 0);

        // z = acc0 + acc1 -> tanh -> bf16 -> one b64 LDS write.
        const float h0 = fast_tanh(acc0[0] + acc1[0]);
        const float h1 = fast_tanh(acc0[1] + acc1[1]);
        const float h2 = fast_tanh(acc0[2] + acc1[2]);
        const float h3 = fast_tanh(acc0[3] + acc1[3]);
        uint2 pk;
        pk.x = pack2bf(h0, h1);
        pk.y = pack2bf(h2, h3);
        *(uint2*)(wbuf + wr_off) = pk;

        LGKM_BARRIER();   // drains LDS only; pe prefetch stays outstanding

        xpc = xpn;
        xpn = xp2;
    }

    // Final h is in ht0 (t=511 wrote ht0), B-fragment order. Linear head.
    if (tid < 16 * OUTc) {
        const int bb = tid >> 1, o = tid & 1;
        float s = b_lin[o];
        const float* wl = W_lin + o * Hc;
#pragma unroll 8
        for (int k = 0; k < Hc; ++k) {
            const int off = ((k >> 5) << 9) + (((k >> 3) & 3) * 16 + bb) * 8 + (k & 7);
            s = fmaf(bf2f(ht0[off]), wl[k], s);
        }
        out[(blk * 16 + bb) * OUTc + o] = s;
    }
}

extern "C" void kernel_launch(void* const* d_in, const int* in_sizes, int n_in,
                              void* d_out, int out_size, void* d_ws, size_t ws_size,
                              hipStream_t stream) {
    const int*   inputs    = (const int*)d_in[0];
    const float* emb_table = (const float*)d_in[1];
    const float* W_ih      = (const float*)d_in[2];
    const float* W_hh      = (const float*)d_in[3];
    const float* b_ih      = (const float*)d_in[4];
    const float* b_hh      = (const float*)d_in[5];
    const float* W_lin     = (const float*)d_in[6];
    const float* b_lin     = (const float*)d_in[7];
    float* out = (float*)d_out;

    float* pe = (float*)d_ws;  // VOCAB*H*4 = 2.26 MB
    pe_kernel<<<VOCAB, Hc, 0, stream>>>(emb_table, W_ih, b_ih, b_hh, pe);
    rnn_mfma<<<Bc / 16, 512, 0, stream>>>(inputs, pe, W_hh, W_lin, b_lin, out);
}